// Round 7
// baseline (490.508 us; speedup 1.0000x reference)
//
#include <hip/hip_runtime.h>
#include <hip/hip_bf16.h>

// ---------------- types & helpers ----------------
typedef short bf16x8 __attribute__((ext_vector_type(8)));
typedef float f32x4  __attribute__((ext_vector_type(4)));
typedef unsigned short u16x4 __attribute__((ext_vector_type(4)));

#define CDIM   768
#define NQKV   2304
#define MROWS  8192
#define TSEQ   2048
#define HD     64
#define NHEAD  12
#define BHTOT  48
#define NBLK   512

__device__ __forceinline__ unsigned short f2bf(float f) {
    unsigned int x;
    __builtin_memcpy(&x, &f, 4);
    unsigned int r = (x + 0x7fffu + ((x >> 16) & 1u)) >> 16;
    return (unsigned short)r;
}

__device__ __forceinline__ unsigned int pkbf(float a, float b) {
    unsigned int ua, ub;
    __builtin_memcpy(&ua, &a, 4);
    __builtin_memcpy(&ub, &b, 4);
    return __builtin_amdgcn_perm(ua + 0x8000u, ub + 0x8000u, 0x03020706u);
}

__device__ __forceinline__ f32x4 mfma16(bf16x8 a, bf16x8 b, f32x4 c) {
    return __builtin_amdgcn_mfma_f32_16x16x32_bf16(a, b, c, 0, 0, 0);
}

__device__ __forceinline__ void gl_lds16(const unsigned short* g, unsigned short* l) {
    __builtin_amdgcn_global_load_lds(
        (__attribute__((address_space(1))) void*)(g),
        (__attribute__((address_space(3))) void*)(l),
        16, 0, 0);
}

// software grid barrier: all NBLK blocks co-resident by construction
__device__ __forceinline__ void gbar(unsigned int* ctr) {
    __syncthreads();
    if (threadIdx.x == 0) {
        __threadfence();  // release all prior writes device-wide
        __hip_atomic_fetch_add(ctr, 1u, __ATOMIC_RELEASE, __HIP_MEMORY_SCOPE_AGENT);
        while (__hip_atomic_load(ctr, __ATOMIC_ACQUIRE, __HIP_MEMORY_SCOPE_AGENT) <
               (unsigned)NBLK)
            __builtin_amdgcn_s_sleep(1);
        __threadfence();
    }
    __syncthreads();
}

// ---------------- fused persistent kernel ----------------
__global__ __launch_bounds__(256, 2) void mega(
    const float* __restrict__ X, const float* __restrict__ W,
    const float* __restrict__ Bias, unsigned int* __restrict__ bar,
    unsigned short* __restrict__ Xb, unsigned short* __restrict__ Wt,
    unsigned short* __restrict__ Q, unsigned short* __restrict__ Km,
    unsigned short* __restrict__ Vt, float* __restrict__ Out)
{
    __shared__ __align__(16) unsigned short SH[16384];  // 32 KB, re-used per stage

    const int tid  = threadIdx.x;
    const int blk  = blockIdx.x;           // 0..511
    const int wave = tid >> 6, lane = tid & 63;
    const int quad = lane >> 4, m16 = lane & 15;

    // ================= stage 0: transpose W + convert X =================
    if (blk < 432) {
        unsigned short (*tile)[72] = (unsigned short (*)[72])SH;
        const int bx = blk % 36, by = blk / 36;
#pragma unroll
        for (int c = 0; c < 4; c++) {
            int chunk = tid + 256 * c;
            int r = chunk >> 4, cc = chunk & 15;
            f32x4 v = *(const f32x4*)(W + (size_t)(by * 64 + r) * NQKV + bx * 64 + cc * 4);
#pragma unroll
            for (int j = 0; j < 4; j++) tile[cc * 4 + j][r] = f2bf(v[j]);
        }
        __syncthreads();
#pragma unroll
        for (int c = 0; c < 2; c++) {
            int chunk = tid + 256 * c;
            int r = chunk >> 3, cc = chunk & 7;
            bf16x8 v;
#pragma unroll
            for (int j = 0; j < 8; j++) v[j] = (short)tile[r][cc * 8 + j];
            *(bf16x8*)(Wt + (size_t)(bx * 64 + r) * CDIM + by * 64 + cc * 8) = v;
        }
    }
    // X convert: 1,572,864 f32x4 chunks = 512*256*12 exactly
#pragma unroll 1
    for (int c = 0; c < 12; c++) {
        size_t i4 = (size_t)c * NBLK * 256 + (size_t)blk * 256 + tid;
        f32x4 v = *(const f32x4*)(X + i4 * 4);
        u16x4 o;
#pragma unroll
        for (int j = 0; j < 4; j++) o[j] = f2bf(v[j]);
        *(u16x4*)(Xb + i4 * 4) = o;
    }
    gbar(&bar[0]);

    // ================= stage 1: QKV GEMM (BM=BN=128, BK=64) =================
    {
        unsigned short* As = SH;
        unsigned short* Bs = SH + 8192;
        const int wr = wave >> 1, wc = wave & 1;
        const int srow[4] = {
            (wave * 256 + 0 * 64 + lane) >> 3, (wave * 256 + 1 * 64 + lane) >> 3,
            (wave * 256 + 2 * 64 + lane) >> 3, (wave * 256 + 3 * 64 + lane) >> 3 };
        const int spos = lane & 7;
        const int rb = m16 & 7;
        const int ntile = (blk < 128) ? 3 : 2;

#pragma unroll 1
        for (int tt = 0; tt < ntile; tt++) {
            const int t = blk + tt * NBLK;          // 0..1151
            const int xcd = t & 7, s = t >> 3;      // s: 0..143
            const int m0 = (xcd * 8 + (s & 7)) * 128;
            const int n0 = (s >> 3) * 128;

            f32x4 acc[4][4];
#pragma unroll
            for (int i = 0; i < 4; i++)
#pragma unroll
                for (int j = 0; j < 4; j++) acc[i][j] = f32x4{0.f, 0.f, 0.f, 0.f};

            const unsigned short* xb = Xb + (size_t)m0 * CDIM;
            const unsigned short* wb = Wt + (size_t)n0 * CDIM;

            for (int k0 = 0; k0 < CDIM; k0 += 64) {
#pragma unroll
                for (int c = 0; c < 4; c++) {
                    int row = srow[c];
                    int ch = spos ^ (row & 7);
                    gl_lds16(xb + (size_t)row * CDIM + k0 + ch * 8, As + wave * 2048 + c * 512);
                    gl_lds16(wb + (size_t)row * CDIM + k0 + ch * 8, Bs + wave * 2048 + c * 512);
                }
                __syncthreads();
#pragma unroll
                for (int ks = 0; ks < 2; ks++) {
                    bf16x8 af[4], bfg[4];
#pragma unroll
                    for (int u = 0; u < 4; u++) {
                        int rowa = wr * 64 + u * 16 + m16;
                        int rowb = wc * 64 + u * 16 + m16;
                        int pos = (ks * 4 + quad) ^ rb;
                        af[u]  = *(const bf16x8*)(As + rowa * 64 + pos * 8);
                        bfg[u] = *(const bf16x8*)(Bs + rowb * 64 + pos * 8);
                    }
#pragma unroll
                    for (int i = 0; i < 4; i++)
#pragma unroll
                        for (int j = 0; j < 4; j++)
                            acc[i][j] = mfma16(af[i], bfg[j], acc[i][j]);
                }
                __syncthreads();
            }

            const int region = n0 / CDIM;
            const float qscale = (region == 0) ? 0.125f : 1.0f;
#pragma unroll
            for (int i = 0; i < 4; i++) {
                int row = m0 + wr * 64 + i * 16 + quad * 4;
#pragma unroll
                for (int j = 0; j < 4; j++) {
                    int gcol = n0 + wc * 64 + j * 16 + m16;
                    int cc = gcol - region * CDIM;
                    int h = cc >> 6, d = cc & 63;
                    float bv = Bias[gcol];
#pragma unroll
                    for (int r = 0; r < 4; r++) {
                        int gm = row + r;
                        int b = gm >> 11, tq = gm & 2047;
                        int bh = b * NHEAD + h;
                        unsigned short o = f2bf((acc[i][j][r] + bv) * qscale);
                        if (region == 0)      Q[((size_t)bh * TSEQ + tq) * HD + d] = o;
                        else if (region == 1) Km[((size_t)bh * TSEQ + tq) * HD + d] = o;
                        else                  Vt[((size_t)bh * HD + d) * TSEQ + tq] = o;
                    }
                }
            }
        }
    }
    gbar(&bar[1]);

    // ================= stage 2: causal relu-attention =================
    {
        unsigned short* SK = SH;
        unsigned short* SV = SH + 8192;
        const int q4 = quad, q8 = m16 >> 2, m3 = m16 & 3;

        // per-XCD decode: u = blk>>3 in [0,64); 6 heads x 10 jobs, u>=60 idle
        const int xcd = blk & 7, u = blk >> 3;
        int jb_it[2], nj = 0, bh = 0;
        if (u < 60) {
            bh = xcd * 6 + u / 10;
            int r = u % 10;
            if (r < 4) { jb_it[0] = 15 - r; jb_it[1] = 0; nj = 1; }
            else       { int p = r - 4; jb_it[0] = 11 - p; jb_it[1] = p; nj = 2; }
        }

        const int fr  = ((q8 & 1) << 2) | m3;
        const int kx0 = (q4 ^ fr) * 8;
        const int kx1 = kx0 ^ 32;
        const int krb = (q8 * 8 + m3) * 64;

        const unsigned short* qb = Q  + (size_t)bh * TSEQ * HD;
        const unsigned short* kb = Km + (size_t)bh * TSEQ * HD;
        const unsigned short* vb = Vt + (size_t)bh * HD * TSEQ;

#pragma unroll 1
        for (int jj = 0; jj < nj; jj++) {
            const int it = jb_it[jj];
            const int i0 = it * 128;

            bf16x8 qf[2][2];
#pragma unroll
            for (int si = 0; si < 2; si++)
#pragma unroll
                for (int ks = 0; ks < 2; ks++)
                    qf[si][ks] = *(const bf16x8*)(qb +
                        (size_t)(i0 + wave * 32 + si * 16 + m16) * HD + ks * 32 + q4 * 8);

            f32x4 oacc[2][4];
#pragma unroll
            for (int si = 0; si < 2; si++)
#pragma unroll
                for (int dn = 0; dn < 4; dn++) oacc[si][dn] = f32x4{0.f, 0.f, 0.f, 0.f};

            for (int jt = 0; jt <= it; jt++) {
                const int j0 = jt * 128;
#pragma unroll
                for (int cc = 0; cc < 4; cc++) {
                    int cs = wave * 4 + cc;
                    {
                        int rowK = cs * 8 + (lane >> 3);
                        int chK  = (lane & 7) ^ ((((rowK >> 3) & 1) << 2) | (rowK & 3));
                        gl_lds16(kb + (size_t)(j0 + rowK) * HD + chK * 8, SK + cs * 512);
                    }
                    {
                        int dV  = cs * 4 + (lane >> 4);
                        int chV = (m16 & 8) | ((m16 ^ dV) & 7);
                        gl_lds16(vb + (size_t)dV * TSEQ + j0 + chV * 8, SV + cs * 512);
                    }
                }
                __syncthreads();

                const bool diag = (jt == it);
#pragma unroll
                for (int kk = 0; kk < 4; kk++) {
                    const int kb0 = kk * 2048 + krb;
                    bf16x8 kf_e0 = *(const bf16x8*)(SK + kb0 + kx0);
                    bf16x8 kf_e1 = *(const bf16x8*)(SK + kb0 + kx1);
                    bf16x8 kf_o0 = *(const bf16x8*)(SK + kb0 + 256 + kx0);
                    bf16x8 kf_o1 = *(const bf16x8*)(SK + kb0 + 256 + kx1);

                    f32x4 sacc[2][2];
#pragma unroll
                    for (int o = 0; o < 2; o++)
#pragma unroll
                        for (int si = 0; si < 2; si++) sacc[o][si] = f32x4{0.f, 0.f, 0.f, 0.f};
#pragma unroll
                    for (int si = 0; si < 2; si++) {
                        sacc[0][si] = mfma16(kf_e0, qf[si][0], sacc[0][si]);
                        sacc[0][si] = mfma16(kf_e1, qf[si][1], sacc[0][si]);
                        sacc[1][si] = mfma16(kf_o0, qf[si][0], sacc[1][si]);
                        sacc[1][si] = mfma16(kf_o1, qf[si][1], sacc[1][si]);
                    }

                    unsigned int pk[2][2][2];
#pragma unroll
                    for (int o = 0; o < 2; o++)
#pragma unroll
                        for (int si = 0; si < 2; si++) {
                            f32x4 v = sacc[o][si];
                            if (diag) {
#pragma unroll
                                for (int r = 0; r < 4; r++) {
                                    int gj = kk * 32 + q4 * 8 + o * 4 + r;
                                    int gi = wave * 32 + si * 16 + m16;
                                    if (gj > gi) v[r] = 0.f;
                                }
                            }
#pragma unroll
                            for (int r = 0; r < 4; r++) v[r] = fmaxf(v[r], 0.f);
                            pk[o][si][0] = pkbf(v[0], v[1]);
                            pk[o][si][1] = pkbf(v[2], v[3]);
                        }

#pragma unroll
                    for (int dn = 0; dn < 4; dn++) {
                        int vsw = ((kk * 4 + q4) ^ (m16 & 7)) * 8;
                        bf16x8 vf = *(const bf16x8*)(SV + (dn * 16 + m16) * 128 + vsw);
#pragma unroll
                        for (int si = 0; si < 2; si++) {
                            union { bf16x8 v; unsigned int uu[4]; } af;
                            af.uu[0] = pk[0][si][0];
                            af.uu[1] = pk[0][si][1];
                            af.uu[2] = pk[1][si][0];
                            af.uu[3] = pk[1][si][1];
                            oacc[si][dn] = mfma16(af.v, vf, oacc[si][dn]);
                        }
                    }
                }
                __syncthreads();
            }

            const int b = bh / NHEAD, h = bh % NHEAD;
#pragma unroll
            for (int si = 0; si < 2; si++) {
                int ri = i0 + wave * 32 + si * 16 + q4 * 4;
#pragma unroll
                for (int dn = 0; dn < 4; dn++) {
                    int d = dn * 16 + m16;
#pragma unroll
                    for (int r = 0; r < 4; r++) {
                        Out[((size_t)b * TSEQ + ri + r) * CDIM + h * HD + d] = oacc[si][dn][r];
                    }
                }
            }
        }
    }
}

// ---------------- launch ----------------
extern "C" void kernel_launch(void* const* d_in, const int* in_sizes, int n_in,
                              void* d_out, int out_size, void* d_ws, size_t ws_size,
                              hipStream_t stream) {
    const float* X    = (const float*)d_in[0];
    const float* W    = (const float*)d_in[1];
    const float* Bias = (const float*)d_in[2];
    float* out = (float*)d_out;

    unsigned int*   bar = (unsigned int*)d_ws;                 // 64 B
    unsigned short* Xb  = (unsigned short*)d_ws + 32;          // 8192*768
    unsigned short* Wt  = Xb + (size_t)MROWS * CDIM;           // 2304*768
    unsigned short* Q   = Wt + (size_t)NQKV * CDIM;
    unsigned short* Km  = Q  + (size_t)BHTOT * TSEQ * HD;
    unsigned short* Vt  = Km + (size_t)BHTOT * TSEQ * HD;

    hipMemsetAsync(bar, 0, 64, stream);
    hipLaunchKernelGGL(mega, dim3(NBLK), dim3(256), 0, stream,
                       X, W, Bias, bar, Xb, Wt, Q, Km, Vt, out);
}

// Round 8
// 177.972 us; speedup vs baseline: 2.7561x; 2.7561x over previous
//
#include <hip/hip_runtime.h>
#include <hip/hip_bf16.h>

// ---------------- types & helpers ----------------
typedef short bf16x8 __attribute__((ext_vector_type(8)));
typedef float f32x4  __attribute__((ext_vector_type(4)));
typedef unsigned short u16x4 __attribute__((ext_vector_type(4)));

#define CDIM   768
#define NQKV   2304
#define MROWS  8192
#define TSEQ   2048
#define HD     64
#define NHEAD  12
#define BHTOT  48

__device__ __forceinline__ unsigned short f2bf(float f) {
    unsigned int x;
    __builtin_memcpy(&x, &f, 4);
    unsigned int r = (x + 0x7fffu + ((x >> 16) & 1u)) >> 16;
    return (unsigned short)r;
}

__device__ __forceinline__ unsigned int pkbf(float a, float b) {
    unsigned int ua, ub;
    __builtin_memcpy(&ua, &a, 4);
    __builtin_memcpy(&ub, &b, 4);
    return __builtin_amdgcn_perm(ua + 0x8000u, ub + 0x8000u, 0x03020706u);
}

__device__ __forceinline__ f32x4 mfma16(bf16x8 a, bf16x8 b, f32x4 c) {
    return __builtin_amdgcn_mfma_f32_16x16x32_bf16(a, b, c, 0, 0, 0);
}

__device__ __forceinline__ void gl_lds16(const unsigned short* g, unsigned short* l) {
    __builtin_amdgcn_global_load_lds(
        (__attribute__((address_space(1))) void*)(g),
        (__attribute__((address_space(3))) void*)(l),
        16, 0, 0);
}

// ---------------- kernel 0: prep = W transpose+cvt + X cvt ----------------
__global__ __launch_bounds__(256) void prep(
    const float* __restrict__ X, const float* __restrict__ W,
    unsigned short* __restrict__ Xb, unsigned short* __restrict__ Wt)
{
    const int tid = threadIdx.x, blk = blockIdx.x;
    if (blk < 432) {
        __shared__ __align__(16) unsigned short tile[64][72];
        const int bx = blk % 36, by = blk / 36;
#pragma unroll
        for (int c = 0; c < 4; c++) {
            int chunk = tid + 256 * c;
            int r = chunk >> 4, cc = chunk & 15;
            f32x4 v = *(const f32x4*)(W + (size_t)(by * 64 + r) * NQKV + bx * 64 + cc * 4);
#pragma unroll
            for (int j = 0; j < 4; j++) tile[cc * 4 + j][r] = f2bf(v[j]);
        }
        __syncthreads();
#pragma unroll
        for (int c = 0; c < 2; c++) {
            int chunk = tid + 256 * c;
            int r = chunk >> 3, cc = chunk & 7;
            bf16x8 v;
#pragma unroll
            for (int j = 0; j < 8; j++) v[j] = (short)tile[r][cc * 8 + j];
            *(bf16x8*)(Wt + (size_t)(bx * 64 + r) * CDIM + by * 64 + cc * 8) = v;
        }
    }
    for (size_t i4 = (size_t)blk * 256 + tid; i4 < (size_t)(MROWS * CDIM / 4);
         i4 += (size_t)448 * 256) {
        f32x4 v = *(const f32x4*)(X + i4 * 4);
        u16x4 o;
#pragma unroll
        for (int j = 0; j < 4; j++) o[j] = f2bf(v[j]);
        *(u16x4*)(Xb + i4 * 4) = o;
    }
}

// ---------------- kernel 1: QKV GEMM (BM=256, BN=128, BK=64, 512 thr) ----------------
// 8 waves, each computes 64x64. XOR-swizzled LDS, conflict-free b128 reads.
// Q pre-scaled by 0.125. XCD-colocated: 4 m-tiles of X per XCD (~1.6 MB in L2).
#define BK 64

__global__ __launch_bounds__(512, 4) void qkv_gemm(
    const unsigned short* __restrict__ X,    // (8192, 768) bf16
    const unsigned short* __restrict__ Wt,   // (2304, 768) bf16
    const float* __restrict__ Bias,          // (2304) fp32
    unsigned short* __restrict__ Q,
    unsigned short* __restrict__ Km,
    unsigned short* __restrict__ Vt)
{
    __shared__ __align__(16) unsigned short As[256 * BK];  // 32 KB
    __shared__ __align__(16) unsigned short Bs[128 * BK];  // 16 KB
    const int tid  = threadIdx.x;
    const int wave = tid >> 6, lane = tid & 63;
    const int quad = lane >> 4, m16 = lane & 15;
    const int wr = wave >> 1, wc = wave & 1;   // wr: 0..3 (64-row), wc: 0..1 (64-col)

    const int t   = blockIdx.x;                // 0..575
    const int xcd = t & 7, s = t >> 3;         // s: 0..71
    const int m0  = (xcd * 4 + (s & 3)) * 256;
    const int n0  = (s >> 2) * 128;

    f32x4 acc[4][4];
#pragma unroll
    for (int i = 0; i < 4; i++)
#pragma unroll
        for (int j = 0; j < 4; j++) acc[i][j] = f32x4{0.f, 0.f, 0.f, 0.f};

    const unsigned short* xb = X + (size_t)m0 * CDIM;
    const unsigned short* wb = Wt + (size_t)n0 * CDIM;

    const int spos = lane & 7;
    const int rb = m16 & 7;
    // As slots: wave*256 + c*64 + lane (c<4); Bs slots: wave*128 + c*64 + lane (c<2)
    int arow[4], brow[2];
#pragma unroll
    for (int c = 0; c < 4; c++) arow[c] = (wave * 256 + c * 64 + lane) >> 3;
#pragma unroll
    for (int c = 0; c < 2; c++) brow[c] = (wave * 128 + c * 64 + lane) >> 3;

    for (int k0 = 0; k0 < CDIM; k0 += BK) {
#pragma unroll
        for (int c = 0; c < 4; c++) {
            int row = arow[c], ch = spos ^ (row & 7);
            gl_lds16(xb + (size_t)row * CDIM + k0 + ch * 8, As + wave * 2048 + c * 512);
        }
#pragma unroll
        for (int c = 0; c < 2; c++) {
            int row = brow[c], ch = spos ^ (row & 7);
            gl_lds16(wb + (size_t)row * CDIM + k0 + ch * 8, Bs + wave * 1024 + c * 512);
        }
        __syncthreads();
#pragma unroll
        for (int ks = 0; ks < 2; ks++) {
            bf16x8 af[4], bfg[4];
#pragma unroll
            for (int u = 0; u < 4; u++) {
                int rowa = wr * 64 + u * 16 + m16;
                int rowb = wc * 64 + u * 16 + m16;
                int pos = (ks * 4 + quad) ^ rb;
                af[u]  = *(const bf16x8*)(As + rowa * 64 + pos * 8);
                bfg[u] = *(const bf16x8*)(Bs + rowb * 64 + pos * 8);
            }
#pragma unroll
            for (int i = 0; i < 4; i++)
#pragma unroll
                for (int j = 0; j < 4; j++)
                    acc[i][j] = mfma16(af[i], bfg[j], acc[i][j]);
        }
        __syncthreads();
    }

    const int region = n0 / CDIM;
    const float qscale = (region == 0) ? 0.125f : 1.0f;
#pragma unroll
    for (int i = 0; i < 4; i++) {
        int row = m0 + wr * 64 + i * 16 + quad * 4;
#pragma unroll
        for (int j = 0; j < 4; j++) {
            int gcol = n0 + wc * 64 + j * 16 + m16;
            int cc = gcol - region * CDIM;
            int h = cc >> 6, d = cc & 63;
            float bv = Bias[gcol];
#pragma unroll
            for (int r = 0; r < 4; r++) {
                int gm = row + r;
                int b = gm >> 11, tq = gm & 2047;
                int bh = b * NHEAD + h;
                unsigned short o = f2bf((acc[i][j][r] + bv) * qscale);
                if (region == 0)      Q[((size_t)bh * TSEQ + tq) * HD + d] = o;
                else if (region == 1) Km[((size_t)bh * TSEQ + tq) * HD + d] = o;
                else                  Vt[((size_t)bh * HD + d) * TSEQ + tq] = o;
            }
        }
    }
}

// ---------------- kernel 2: causal relu-attention (S^T formulation, R5) ----------------
#define LDSK 0
#define LDSV 8192

__global__ __launch_bounds__(256, 4) void attn(
    const unsigned short* __restrict__ Q,
    const unsigned short* __restrict__ Kmat,
    const unsigned short* __restrict__ Vt,
    float* __restrict__ Out)
{
    __shared__ __align__(16) unsigned short S[16384];  // K 16KB | V 16KB

    const int tid  = threadIdx.x;
    const int wave = tid >> 6, lane = tid & 63;
    const int q4 = lane >> 4, m16 = lane & 15;
    const int q8 = m16 >> 2, m3 = m16 & 3;

    const int xcd = blockIdx.x & 7;
    const int idx = blockIdx.x >> 3;        // 0..95
    const int bh  = xcd * 6 + (idx % 6);
    const int it  = 15 - (idx / 6);
    const int i0  = it * 128;

    const unsigned short* qb = Q    + (size_t)bh * TSEQ * HD;
    const unsigned short* kb = Kmat + (size_t)bh * TSEQ * HD;
    const unsigned short* vb = Vt   + (size_t)bh * HD * TSEQ;

    bf16x8 qf[2][2];
#pragma unroll
    for (int si = 0; si < 2; si++)
#pragma unroll
        for (int ks = 0; ks < 2; ks++)
            qf[si][ks] = *(const bf16x8*)(qb +
                (size_t)(i0 + wave * 32 + si * 16 + m16) * HD + ks * 32 + q4 * 8);

    f32x4 oacc[2][4];
#pragma unroll
    for (int si = 0; si < 2; si++)
#pragma unroll
        for (int dn = 0; dn < 4; dn++) oacc[si][dn] = f32x4{0.f, 0.f, 0.f, 0.f};

    const int fr  = ((q8 & 1) << 2) | m3;
    const int kx0 = (q4 ^ fr) * 8;
    const int kx1 = kx0 ^ 32;
    const int krb = (q8 * 8 + m3) * 64;

    for (int jt = 0; jt <= it; jt++) {
        const int j0 = jt * 128;
#pragma unroll
        for (int cc = 0; cc < 4; cc++) {
            int cs = wave * 4 + cc;
            {
                int rowK = cs * 8 + (lane >> 3);
                int chK  = (lane & 7) ^ ((((rowK >> 3) & 1) << 2) | (rowK & 3));
                gl_lds16(kb + (size_t)(j0 + rowK) * HD + chK * 8, &S[LDSK] + cs * 512);
            }
            {
                int dV  = cs * 4 + (lane >> 4);
                int chV = (m16 & 8) | ((m16 ^ dV) & 7);
                gl_lds16(vb + (size_t)dV * TSEQ + j0 + chV * 8, &S[LDSV] + cs * 512);
            }
        }
        __syncthreads();

        const bool diag = (jt == it);
#pragma unroll
        for (int kk = 0; kk < 4; kk++) {
            const int kb0 = kk * 2048 + krb;
            bf16x8 kf_e0 = *(const bf16x8*)(&S[LDSK] + kb0 + kx0);
            bf16x8 kf_e1 = *(const bf16x8*)(&S[LDSK] + kb0 + kx1);
            bf16x8 kf_o0 = *(const bf16x8*)(&S[LDSK] + kb0 + 256 + kx0);
            bf16x8 kf_o1 = *(const bf16x8*)(&S[LDSK] + kb0 + 256 + kx1);

            f32x4 sacc[2][2];
#pragma unroll
            for (int o = 0; o < 2; o++)
#pragma unroll
                for (int si = 0; si < 2; si++) sacc[o][si] = f32x4{0.f, 0.f, 0.f, 0.f};
#pragma unroll
            for (int si = 0; si < 2; si++) {
                sacc[0][si] = mfma16(kf_e0, qf[si][0], sacc[0][si]);
                sacc[0][si] = mfma16(kf_e1, qf[si][1], sacc[0][si]);
                sacc[1][si] = mfma16(kf_o0, qf[si][0], sacc[1][si]);
                sacc[1][si] = mfma16(kf_o1, qf[si][1], sacc[1][si]);
            }

            unsigned int pk[2][2][2];
#pragma unroll
            for (int o = 0; o < 2; o++)
#pragma unroll
                for (int si = 0; si < 2; si++) {
                    f32x4 v = sacc[o][si];
                    if (diag) {
#pragma unroll
                        for (int r = 0; r < 4; r++) {
                            int gj = kk * 32 + q4 * 8 + o * 4 + r;
                            int gi = wave * 32 + si * 16 + m16;
                            if (gj > gi) v[r] = 0.f;
                        }
                    }
#pragma unroll
                    for (int r = 0; r < 4; r++) v[r] = fmaxf(v[r], 0.f);
                    pk[o][si][0] = pkbf(v[0], v[1]);
                    pk[o][si][1] = pkbf(v[2], v[3]);
                }

#pragma unroll
            for (int dn = 0; dn < 4; dn++) {
                int vsw = ((kk * 4 + q4) ^ (m16 & 7)) * 8;
                bf16x8 vf = *(const bf16x8*)(&S[LDSV] + (dn * 16 + m16) * 128 + vsw);
#pragma unroll
                for (int si = 0; si < 2; si++) {
                    union { bf16x8 v; unsigned int u[4]; } af;
                    af.u[0] = pk[0][si][0];
                    af.u[1] = pk[0][si][1];
                    af.u[2] = pk[1][si][0];
                    af.u[3] = pk[1][si][1];
                    oacc[si][dn] = mfma16(af.v, vf, oacc[si][dn]);
                }
            }
        }
        __syncthreads();
    }

    const int b = bh / NHEAD, h = bh % NHEAD;
#pragma unroll
    for (int si = 0; si < 2; si++) {
        int ri = i0 + wave * 32 + si * 16 + q4 * 4;
#pragma unroll
        for (int dn = 0; dn < 4; dn++) {
            int d = dn * 16 + m16;
#pragma unroll
            for (int r = 0; r < 4; r++) {
                Out[((size_t)b * TSEQ + ri + r) * CDIM + h * HD + d] = oacc[si][dn][r];
            }
        }
    }
}

// ---------------- launch ----------------
extern "C" void kernel_launch(void* const* d_in, const int* in_sizes, int n_in,
                              void* d_out, int out_size, void* d_ws, size_t ws_size,
                              hipStream_t stream) {
    const float* X    = (const float*)d_in[0];
    const float* W    = (const float*)d_in[1];
    const float* Bias = (const float*)d_in[2];
    float* out = (float*)d_out;

    unsigned short* Xb = (unsigned short*)d_ws;
    unsigned short* Wt = Xb + (size_t)MROWS * CDIM;
    unsigned short* Q  = Wt + (size_t)NQKV * CDIM;
    unsigned short* Km = Q  + (size_t)BHTOT * TSEQ * HD;
    unsigned short* Vt = Km + (size_t)BHTOT * TSEQ * HD;

    hipLaunchKernelGGL(prep, dim3(448), dim3(256), 0, stream, X, W, Xb, Wt);
    hipLaunchKernelGGL(qkv_gemm, dim3(576), dim3(512), 0, stream,
                       Xb, Wt, Bias, Q, Km, Vt);
    hipLaunchKernelGGL(attn, dim3(BHTOT * 16), dim3(256), 0, stream, Q, Km, Vt, out);
}